// Round 12
// baseline (169.409 us; speedup 1.0000x reference)
//
#include <hip/hip_runtime.h>
#include <cstdint>
#include <cstddef>

// ---------------------------------------------------------------------------
// DeMash = complex GEMM: out[bts, m] = sum_l y[bts, l] * conj(C)[m, l]
//   out_r = Yr@Cr^T + Yi@Ci^T ; out_i = Yi@Cr^T - Yr@Ci^T
//
// R19: high-TLP small tile -- the one untested occupancy point. All
// schedule variants (R10-R16) failed; R18's gemm works via cross-block
// phase-staggered overlap at 3 blocks/CU (MfmaUtil 33 + VALU 14 = 47%:
// half the cycles all 3 blocks share a drain). This doubles the stagger:
//   tile 32M x 64N' (4 waves 2x2, each 16M x 32N'), grid 24x64 = 1536
//   blocks = 6/CU, LDS 8+16 = 24 KB (6x24 = 144 <= 160), 24 waves/CU.
// acc halves to 32 VGPR -> ~70 total, within the <=85 cap for 24
// waves/CU (__launch_bounds__(256,6)). Costs: W staged per bm-group
// (302 -> 604 MB), but bn-grouped XCD swizzle (kept from R18, gemm
// -2.3 us measured) makes those re-reads L2-hits in a 1.18 MB/XCD
// working set. A staging + ds_read volume + reads/MFMA (0.75) unchanged.
// 2-barrier single-buffer loop unchanged (proven optimum schedule).
//   A2 [2048][3072] fp16 : [Yr(1536, zero-padded from 1512) | Yi(1536)]
//   W2 [1536][3072] fp16 : [Cr(1536) | Ci(1536)]
// prep_all = R15 vectorized (unchanged).
// ---------------------------------------------------------------------------

typedef _Float16 half_t;
typedef half_t half8 __attribute__((ext_vector_type(8)));
typedef half_t half4 __attribute__((ext_vector_type(4)));
typedef half_t half2_t __attribute__((ext_vector_type(2)));
typedef float floatx4 __attribute__((ext_vector_type(4)));
typedef float floatv4 __attribute__((ext_vector_type(4)));
typedef float floatv2 __attribute__((ext_vector_type(2)));

#define M_DIM 2048
#define K_DIM 3072            // [Yr 1536 | Yi 1536]
#define L_PAD 1536            // 1512 padded to 24*64
#define N2_DIM 1536           // W2 rows (n' padded)
#define LDIM 1512
#define NSC 108
#define SYMS 14
#define FFT 128
#define GUARD 10
#define ROWLEN (SYMS * FFT)   // 1792

#define BM 32                 // M tile
#define BN 64                 // N' tile (complex columns)
#define BK 64                 // l-step per iteration
#define NITER (L_PAD / BK)    // 24

// prep grid partition (blocks of 256 threads)
#define PA_BLOCKS 3024    // A: 2048 rows x 14 syms x 27 j-quads / 256
#define PW_BLOCKS 4608    // W2: 1536 rows x 768 k-quads / 256
#define PP_BLOCKS 48      // A pad zero: 2048 x 48 halves / 8 / 256
#define PG_BLOCKS 2240    // guard zero: 4096 x 14 x 10 float2 / 256
#define PREP_BLOCKS (PA_BLOCKS + PW_BLOCKS + PP_BLOCKS + PG_BLOCKS)

typedef __attribute__((address_space(3))) uint32_t lds_u32_t;
typedef const __attribute__((address_space(1))) uint32_t glob_u32_t;

__device__ __forceinline__ void gl2lds16(const void* g, void* l) {
    __builtin_amdgcn_global_load_lds((glob_u32_t*)g, (lds_u32_t*)l, 16, 0, 0);
}

// ---------------------------------------------------------------------------
// prep_all: R15 vectorized version (unchanged).
// ---------------------------------------------------------------------------
__global__ __launch_bounds__(256) void prep_all(
    const float* __restrict__ xr, const float* __restrict__ xi,
    const float* __restrict__ Cr, const float* __restrict__ Ci,
    const int* __restrict__ sc,
    half_t* __restrict__ A, half_t* __restrict__ W, float* __restrict__ out)
{
    const int b = blockIdx.x;
    const int t = threadIdx.x;

    if (b < PA_BLOCKS) {
        int idx = b * 256 + t;          // [0, 2048*14*27)
        int jq = idx % 27;
        int rest = idx / 27;
        int sym = rest % 14;
        int row = rest / 14;
        int s0 = sc[4 * jq];            // contiguous subcarriers s0..s0+3
        const float* xrp = xr + (size_t)row * ROWLEN + sym * FFT + s0;
        const float* xip = xi + (size_t)row * ROWLEN + sym * FFT + s0;
        floatv2 r0 = *(const floatv2*)xrp;
        floatv2 r1 = *(const floatv2*)(xrp + 2);
        floatv2 i0 = *(const floatv2*)xip;
        floatv2 i1 = *(const floatv2*)(xip + 2);
        half4 hr = { (half_t)r0.x, (half_t)r0.y, (half_t)r1.x, (half_t)r1.y };
        half4 hi = { (half_t)i0.x, (half_t)i0.y, (half_t)i1.x, (half_t)i1.y };
        size_t dst = (size_t)row * K_DIM + sym * NSC + 4 * jq;
        *(half4*)(A + dst) = hr;
        *(half4*)(A + dst + L_PAD) = hi;
    } else if (b < PA_BLOCKS + PW_BLOCKS) {
        int idx = (b - PA_BLOCKS) * 256 + t;   // [0, 1536*768)
        int kq = idx % 768;
        int n = idx / 768;
        int k0 = kq * 4;
        floatv4 f = {0.0f, 0.0f, 0.0f, 0.0f};
        if (n < LDIM) {
            if (k0 < L_PAD) {
                if (k0 < LDIM)
                    f = *(const floatv4*)(Cr + (size_t)n * LDIM + k0);
            } else {
                int l = k0 - L_PAD;
                if (l < LDIM)
                    f = *(const floatv4*)(Ci + (size_t)n * LDIM + l);
            }
        }
        half4 h = { (half_t)f.x, (half_t)f.y, (half_t)f.z, (half_t)f.w };
        *(half4*)(W + (size_t)n * K_DIM + k0) = h;
    } else if (b < PA_BLOCKS + PW_BLOCKS + PP_BLOCKS) {
        int idx = (b - PA_BLOCKS - PW_BLOCKS) * 256 + t;  // [0, 12288)
        int c = idx % 6;
        int row = idx / 6;
        int col = (c < 3) ? (LDIM + c * 8) : (L_PAD + LDIM + (c - 3) * 8);
        half8 z = {};
        *(half8*)(A + (size_t)row * K_DIM + col) = z;
    } else {
        // zero guard cols as float2 pairs: (0,1)..(8,9), (118,119)..(126,127)
        int idx = (b - PA_BLOCKS - PW_BLOCKS - PP_BLOCKS) * 256 + t;
        int h = idx % 10;
        int rest = idx / 10;
        int sym = rest % 14;
        int rowri = rest / 14;                 // [0, 4096) covers both ri
        int c0 = (h < 5) ? (2 * h) : (FFT - GUARD + 2 * (h - 5));
        floatv2 z = {0.0f, 0.0f};
        *(floatv2*)(out + (size_t)rowri * ROWLEN + sym * FFT + c0) = z;
    }
}

// ---------------------------------------------------------------------------
// gemm_scatter: complex 32x64 tile, 4 waves (2x2), each 16M x 32N'
// (1x2 frags x 4 products RR,II,IR,RI). 2-barrier single-buffer BK=64.
// LDS: As[32][128] = 8 KB, Ws[64][128] = 16 KB -> 24 KB; grid 1536
// blocks = 6/CU, 24 waves/CU. XOR chunk swizzle (conflicts 0).
// bn-grouped XCD mapping (R18): xcd = bid&7, k = bid>>3 in [0,192),
// bn = xcd*3 + k%3, bm = k/3 in [0,64). Bijective: 8*3*64 = 1536.
// ---------------------------------------------------------------------------
__global__ __launch_bounds__(256, 6) void gemm_scatter(
    const half_t* __restrict__ A,   // [M_DIM][K_DIM]  [Yr|Yi]
    const half_t* __restrict__ W,   // [N2_DIM][K_DIM] [Cr|Ci]
    const int* __restrict__ sc,
    float* __restrict__ out)        // [2][2048][14][128]; guards pre-zeroed
{
    __shared__ __align__(16) half_t As[BM * 2 * BK];   // 8 KB
    __shared__ __align__(16) half_t Ws[BN * 2 * BK];   // 16 KB

    const int t = threadIdx.x;
    const int bid = blockIdx.x;
    const int k = bid >> 3;           // [0, 192)
    const int bn = (bid & 7) * 3 + (k % 3);
    const int bm = k / 3;             // [0, 64)
    const int lane = t & 63;
    const int w = t >> 6;
    const int wm = (w >> 1) * 16;     // wave M offset in tile
    const int wn = (w & 1) * 32;      // wave N' offset in tile

    floatx4 aRR[2] = {}, aII[2] = {}, aIR[2] = {}, aRI[2] = {};

    // staging: chunk c (16B): row = c>>4, slot = c&15, global chunk
    // g = slot ^ (row&15); g<8 -> Yr/Cr col g*8, g>=8 -> Yi/Ci col
    // 1536+(g-8)*8. LDS dest = base + c*16 (contiguous per lane).
    // As: 512 chunks (2/thread), Ws: 1024 chunks (4/thread).
    const half_t* gA[2];
    const half_t* gW[4];
    half_t* lA[2];
    half_t* lW[4];
#pragma unroll
    for (int r = 0; r < 2; ++r) {
        int c = r * 256 + t;
        int row = c >> 4, slot = c & 15;
        int g = slot ^ (row & 15);
        int gcol = (g < 8) ? g * 8 : (L_PAD + (g - 8) * 8);
        gA[r] = A + (size_t)(bm * BM + row) * K_DIM + gcol;
        lA[r] = As + c * 8;
    }
#pragma unroll
    for (int r = 0; r < 4; ++r) {
        int c = r * 256 + t;
        int row = c >> 4, slot = c & 15;
        int g = slot ^ (row & 15);
        int gcol = (g < 8) ? g * 8 : (L_PAD + (g - 8) * 8);
        gW[r] = W + (size_t)(bn * BN + row) * K_DIM + gcol;
        lW[r] = Ws + c * 8;
    }

    const int fr = lane & 15;         // fragment row (M or N' within 16)
    const int cr = lane >> 4;         // k-quad index within a 32-k step

    for (int kb = 0; kb < NITER; ++kb) {
        __syncthreads();
#pragma unroll
        for (int r = 0; r < 2; ++r) gl2lds16(gA[r], lA[r]);
#pragma unroll
        for (int r = 0; r < 4; ++r) gl2lds16(gW[r], lW[r]);
#pragma unroll
        for (int r = 0; r < 2; ++r) gA[r] += BK;
#pragma unroll
        for (int r = 0; r < 4; ++r) gW[r] += BK;
        __syncthreads();

#pragma unroll
        for (int ss = 0; ss < 2; ++ss) {
            // Yr/Cr global chunk = ss*4+cr; Yi/Ci chunk = 8+ss*4+cr.
            const int sR = ((ss * 4 + cr) ^ fr) * 8;
            const int sI = ((8 + ss * 4 + cr) ^ fr) * 8;
            half8 yr, yi, cRf[2], cIf[2];
            {
                int rb = (wm + fr) * (2 * BK);
                yr = *(const half8*)&As[rb + sR];
                yi = *(const half8*)&As[rb + sI];
            }
#pragma unroll
            for (int j = 0; j < 2; ++j) {
                int rb = (wn + j * 16 + fr) * (2 * BK);
                cRf[j] = *(const half8*)&Ws[rb + sR];
                cIf[j] = *(const half8*)&Ws[rb + sI];
            }
#pragma unroll
            for (int j = 0; j < 2; ++j) {
                aRR[j] = __builtin_amdgcn_mfma_f32_16x16x32_f16(
                    yr, cRf[j], aRR[j], 0, 0, 0);
                aII[j] = __builtin_amdgcn_mfma_f32_16x16x32_f16(
                    yi, cIf[j], aII[j], 0, 0, 0);
                aIR[j] = __builtin_amdgcn_mfma_f32_16x16x32_f16(
                    yi, cRf[j], aIR[j], 0, 0, 0);
                aRI[j] = __builtin_amdgcn_mfma_f32_16x16x32_f16(
                    yr, cIf[j], aRI[j], 0, 0, 0);
            }
        }
    }

    // epilogue: C/D layout col = lane&15 (N'), row = (lane>>4)*4 + reg (M)
    const int rq = lane >> 4;
#pragma unroll
    for (int j = 0; j < 2; ++j) {
        int n = bn * BN + wn + j * 16 + fr;
        if (n >= LDIM) continue;               // N'-pad: discard
        int sym = n / NSC;
        int jj = n - sym * NSC;
        size_t colR = (size_t)sym * FFT + sc[jj];
        size_t colI = (size_t)M_DIM * ROWLEN + colR;
        int m0 = bm * BM + wm + rq * 4;
#pragma unroll
        for (int r = 0; r < 4; ++r) {
            float vr = aRR[j][r] + aII[j][r];
            float vi = aIR[j][r] - aRI[j][r];
            out[colR + (size_t)(m0 + r) * ROWLEN] = vr;
            out[colI + (size_t)(m0 + r) * ROWLEN] = vi;
        }
    }
}

// ---------------------------------------------------------------------------
extern "C" void kernel_launch(void* const* d_in, const int* in_sizes, int n_in,
                              void* d_out, int out_size, void* d_ws, size_t ws_size,
                              hipStream_t stream) {
    const float* xr = (const float*)d_in[0];
    const float* xi = (const float*)d_in[1];
    const float* Cr = (const float*)d_in[2];
    const float* Ci = (const float*)d_in[3];
    const int* sc   = (const int*)d_in[4];
    float* out = (float*)d_out;

    half_t* Ah = (half_t*)d_ws;                                      // 12.58 MB
    half_t* Wh = (half_t*)((char*)d_ws + (size_t)M_DIM * K_DIM * 2); // 9.44 MB

    prep_all<<<PREP_BLOCKS, 256, 0, stream>>>(
        xr, xi, Cr, Ci, sc, Ah, Wh, out);

    gemm_scatter<<<1536, 256, 0, stream>>>(Ah, Wh, sc, out);
}

// Round 13
// 139.530 us; speedup vs baseline: 1.2141x; 1.2141x over previous
//
#include <hip/hip_runtime.h>
#include <cstdint>
#include <cstddef>

// ---------------------------------------------------------------------------
// DeMash = complex GEMM: out[bts, m] = sum_l y[bts, l] * conj(C)[m, l]
//   out_r = Yr@Cr^T + Yi@Ci^T ; out_i = Yi@Cr^T - Yr@Ci^T
//
// R20 = R18 revert (session-best kernel; gemm 45.3 us, total 140.0-140.7).
// FINAL. Full experiment matrix closed (R8-R19):
//   - complex-pairing formulation (R9): staged fragments feed 2 MFMAs
//     each; halved LDS traffic vs real-GEMM form. -11 us. KEPT.
//   - 2-barrier single-buffer, BK=64, 64x64 complex tile, 4 waves 2x2,
//     768 blocks = 3/CU, 12 waves/CU: measured optimum. Regressions:
//     1-barrier dbuf (R10/R11: 68/63), counted vmcnt BK=32 (R12: 61),
//     BK=96 (R13: 50.9), W-direct (R14: 95), counted dbuf BK=64 @
//     2 blocks/CU (R16: 59.5), 32x64 tile @ 6 blocks/CU / 24 waves/CU
//     (R19: 76.4 -- doubled W staging overloads the L2->LDS pipe that
//     is the actual bound; TLP can't fix a volume bottleneck).
//   - bn-grouped XCD swizzle (R18): each XCD's W slice 1.18 MB
//     L2-resident. gemm 47.6 -> 45.3. KEPT. (bm-grouped = R13 regressed.)
//   - prep vectorized (R15): A-build float2->half4, guard float2. KEPT.
//   A2 [2048][3072] fp16 : [Yr(1536, zero-padded from 1512) | Yi(1536)]
//   W2 [1536][3072] fp16 : [Cr(1536) | Ci(1536)]
// XOR chunk swizzle in gemm staging (bank conflicts measured 0).
// ---------------------------------------------------------------------------

typedef _Float16 half_t;
typedef half_t half8 __attribute__((ext_vector_type(8)));
typedef half_t half4 __attribute__((ext_vector_type(4)));
typedef half_t half2_t __attribute__((ext_vector_type(2)));
typedef float floatx4 __attribute__((ext_vector_type(4)));
typedef float floatv4 __attribute__((ext_vector_type(4)));
typedef float floatv2 __attribute__((ext_vector_type(2)));

#define M_DIM 2048
#define K_DIM 3072            // [Yr 1536 | Yi 1536]
#define L_PAD 1536            // 1512 padded to 24*64
#define N2_DIM 1536           // W2 rows (n' padded)
#define LDIM 1512
#define NSC 108
#define SYMS 14
#define FFT 128
#define GUARD 10
#define ROWLEN (SYMS * FFT)   // 1792

#define BM 64
#define BN 64                 // N' tile (complex columns)
#define BK 64                 // l-step per iteration
#define NITER (L_PAD / BK)    // 24

// prep grid partition (blocks of 256 threads)
#define PA_BLOCKS 3024    // A: 2048 rows x 14 syms x 27 j-quads / 256
#define PW_BLOCKS 4608    // W2: 1536 rows x 768 k-quads / 256
#define PP_BLOCKS 48      // A pad zero: 2048 x 48 halves / 8 / 256
#define PG_BLOCKS 2240    // guard zero: 4096 x 14 x 10 float2 / 256
#define PREP_BLOCKS (PA_BLOCKS + PW_BLOCKS + PP_BLOCKS + PG_BLOCKS)

typedef __attribute__((address_space(3))) uint32_t lds_u32_t;
typedef const __attribute__((address_space(1))) uint32_t glob_u32_t;

__device__ __forceinline__ void gl2lds16(const void* g, void* l) {
    __builtin_amdgcn_global_load_lds((glob_u32_t*)g, (lds_u32_t*)l, 16, 0, 0);
}

// ---------------------------------------------------------------------------
// prep_all (one dispatch, 4 regions, wave-uniform region branch):
//  [0, PA): A-build. thread -> (row, sym, jq): 4 consecutive effective
//           subcarriers s0..s0+3 (sc contiguous by construction).
//           2x float2 loads from xr and xi -> half4 stores at
//           A[row][sym*108+4jq] (Yr) and +1536 (Yi). 8B aligned.
//  [PA, +PW): W2-build. row n'<1536: cols [0,1536)=Cr[n'], [1536,3072)=Ci;
//           zero when n'>=1512 or l>=1512. float4 load, half4 store.
//  [.., +PP): A pad zeros (cols 1512..1535 and 3048..3071).
//  [.., +PG): output guard-column zeros as float2: col pairs
//           (0,1)..(8,9) and (118,119)..(126,127), all 8B aligned.
// ---------------------------------------------------------------------------
__global__ __launch_bounds__(256) void prep_all(
    const float* __restrict__ xr, const float* __restrict__ xi,
    const float* __restrict__ Cr, const float* __restrict__ Ci,
    const int* __restrict__ sc,
    half_t* __restrict__ A, half_t* __restrict__ W, float* __restrict__ out)
{
    const int b = blockIdx.x;
    const int t = threadIdx.x;

    if (b < PA_BLOCKS) {
        int idx = b * 256 + t;          // [0, 2048*14*27)
        int jq = idx % 27;
        int rest = idx / 27;
        int sym = rest % 14;
        int row = rest / 14;
        int s0 = sc[4 * jq];            // contiguous subcarriers s0..s0+3
        const float* xrp = xr + (size_t)row * ROWLEN + sym * FFT + s0;
        const float* xip = xi + (size_t)row * ROWLEN + sym * FFT + s0;
        floatv2 r0 = *(const floatv2*)xrp;
        floatv2 r1 = *(const floatv2*)(xrp + 2);
        floatv2 i0 = *(const floatv2*)xip;
        floatv2 i1 = *(const floatv2*)(xip + 2);
        half4 hr = { (half_t)r0.x, (half_t)r0.y, (half_t)r1.x, (half_t)r1.y };
        half4 hi = { (half_t)i0.x, (half_t)i0.y, (half_t)i1.x, (half_t)i1.y };
        size_t dst = (size_t)row * K_DIM + sym * NSC + 4 * jq;
        *(half4*)(A + dst) = hr;
        *(half4*)(A + dst + L_PAD) = hi;
    } else if (b < PA_BLOCKS + PW_BLOCKS) {
        int idx = (b - PA_BLOCKS) * 256 + t;   // [0, 1536*768)
        int kq = idx % 768;
        int n = idx / 768;
        int k0 = kq * 4;
        floatv4 f = {0.0f, 0.0f, 0.0f, 0.0f};
        if (n < LDIM) {
            if (k0 < L_PAD) {
                if (k0 < LDIM)
                    f = *(const floatv4*)(Cr + (size_t)n * LDIM + k0);
            } else {
                int l = k0 - L_PAD;
                if (l < LDIM)
                    f = *(const floatv4*)(Ci + (size_t)n * LDIM + l);
            }
        }
        half4 h = { (half_t)f.x, (half_t)f.y, (half_t)f.z, (half_t)f.w };
        *(half4*)(W + (size_t)n * K_DIM + k0) = h;
    } else if (b < PA_BLOCKS + PW_BLOCKS + PP_BLOCKS) {
        int idx = (b - PA_BLOCKS - PW_BLOCKS) * 256 + t;  // [0, 12288)
        int c = idx % 6;
        int row = idx / 6;
        int col = (c < 3) ? (LDIM + c * 8) : (L_PAD + LDIM + (c - 3) * 8);
        half8 z = {};
        *(half8*)(A + (size_t)row * K_DIM + col) = z;
    } else {
        // zero guard cols as float2 pairs: (0,1)..(8,9), (118,119)..(126,127)
        int idx = (b - PA_BLOCKS - PW_BLOCKS - PP_BLOCKS) * 256 + t;
        int h = idx % 10;
        int rest = idx / 10;
        int sym = rest % 14;
        int rowri = rest / 14;                 // [0, 4096) covers both ri
        int c0 = (h < 5) ? (2 * h) : (FFT - GUARD + 2 * (h - 5));
        floatv2 z = {0.0f, 0.0f};
        *(floatv2*)(out + (size_t)rowri * ROWLEN + sym * FFT + c0) = z;
    }
}

// ---------------------------------------------------------------------------
// gemm_scatter: complex 64x64 tile, 4 waves 2x2, each 32Mx32N' computing
// BOTH out_r and out_i (4 products RR,II,IR,RI via 2x2
// mfma_f32_16x16x32_f16 each). LDS: As[64][128] = [Yr | Yi],
// Ws[64][128] = [Cr | Ci], 32 KB -> 3 blocks/CU, 12 waves/CU.
// XOR chunk swizzle: stage chunk g at slot g^(row&15); read q at q^fr.
// bn-grouped XCD mapping (R18, measured -2.3 us): 1D grid 768,
// xcd = bid&7, k = bid>>3, bn = xcd*3 + k%3, bm = k/3.
// ---------------------------------------------------------------------------
__global__ __launch_bounds__(256, 3) void gemm_scatter(
    const half_t* __restrict__ A,   // [M_DIM][K_DIM]  [Yr|Yi]
    const half_t* __restrict__ W,   // [N2_DIM][K_DIM] [Cr|Ci]
    const int* __restrict__ sc,
    float* __restrict__ out)        // [2][2048][14][128]; guards pre-zeroed
{
    __shared__ __align__(16) half_t As[BM * 2 * BK];   // 16 KB
    __shared__ __align__(16) half_t Ws[BN * 2 * BK];   // 16 KB

    const int t = threadIdx.x;
    // bn-grouped XCD swizzle: XCD (bid&7) owns bn in {3x, 3x+1, 3x+2}
    // for ALL bm -> per-XCD W working set = 1.18 MB (L2-resident).
    const int bid = blockIdx.x;
    const int k = bid >> 3;           // [0, 96)
    const int bn = (bid & 7) * 3 + (k % 3);
    const int bm = k / 3;
    const int lane = t & 63;
    const int w = t >> 6;
    const int wm = (w >> 1) * 32;     // wave M offset in tile
    const int wn = (w & 1) * 32;      // wave N' offset in tile

    floatx4 aRR[2][2] = {}, aII[2][2] = {}, aIR[2][2] = {}, aRI[2][2] = {};

    // staging: chunk c (16B): row = c>>4, slot = c&15, global chunk
    // g = slot ^ (row&15); g<8 -> Yr/Cr col g*8, g>=8 -> Yi/Ci col
    // 1536+(g-8)*8. LDS dest = base + c*16 (contiguous per lane).
    const half_t* gA[4];
    const half_t* gW[4];
    half_t* lA[4];
    half_t* lW[4];
#pragma unroll
    for (int r = 0; r < 4; ++r) {
        int c = r * 256 + t;
        int row = c >> 4, slot = c & 15;
        int g = slot ^ (row & 15);
        int gcol = (g < 8) ? g * 8 : (L_PAD + (g - 8) * 8);
        gA[r] = A + (size_t)(bm * BM + row) * K_DIM + gcol;
        lA[r] = As + c * 8;
        gW[r] = W + (size_t)(bn * BN + row) * K_DIM + gcol;
        lW[r] = Ws + c * 8;
    }

    const int fr = lane & 15;         // fragment row (M or N' within 16)
    const int cr = lane >> 4;         // k-quad index within a 32-k step

    for (int kb = 0; kb < NITER; ++kb) {
        __syncthreads();
#pragma unroll
        for (int r = 0; r < 4; ++r) gl2lds16(gA[r], lA[r]);
#pragma unroll
        for (int r = 0; r < 4; ++r) gl2lds16(gW[r], lW[r]);
#pragma unroll
        for (int r = 0; r < 4; ++r) { gA[r] += BK; gW[r] += BK; }
        __syncthreads();

#pragma unroll
        for (int ss = 0; ss < 2; ++ss) {
            // Yr/Cr global chunk = ss*4+cr; Yi/Ci chunk = 8+ss*4+cr.
            const int sR = ((ss * 4 + cr) ^ fr) * 8;
            const int sI = ((8 + ss * 4 + cr) ^ fr) * 8;
            half8 yr[2], yi[2], cRf[2], cIf[2];
#pragma unroll
            for (int i = 0; i < 2; ++i) {
                int rb = (wm + i * 16 + fr) * (2 * BK);
                yr[i] = *(const half8*)&As[rb + sR];
                yi[i] = *(const half8*)&As[rb + sI];
            }
#pragma unroll
            for (int j = 0; j < 2; ++j) {
                int rb = (wn + j * 16 + fr) * (2 * BK);
                cRf[j] = *(const half8*)&Ws[rb + sR];
                cIf[j] = *(const half8*)&Ws[rb + sI];
            }
#pragma unroll
            for (int i = 0; i < 2; ++i)
#pragma unroll
                for (int j = 0; j < 2; ++j) {
                    aRR[i][j] = __builtin_amdgcn_mfma_f32_16x16x32_f16(
                        yr[i], cRf[j], aRR[i][j], 0, 0, 0);
                    aII[i][j] = __builtin_amdgcn_mfma_f32_16x16x32_f16(
                        yi[i], cIf[j], aII[i][j], 0, 0, 0);
                    aIR[i][j] = __builtin_amdgcn_mfma_f32_16x16x32_f16(
                        yi[i], cRf[j], aIR[i][j], 0, 0, 0);
                    aRI[i][j] = __builtin_amdgcn_mfma_f32_16x16x32_f16(
                        yr[i], cIf[j], aRI[i][j], 0, 0, 0);
                }
        }
    }

    // epilogue: C/D layout col = lane&15 (N'), row = (lane>>4)*4 + reg (M)
    const int rq = lane >> 4;
#pragma unroll
    for (int j = 0; j < 2; ++j) {
        int n = bn * BN + wn + j * 16 + fr;
        if (n >= LDIM) continue;               // N'-pad: discard
        int sym = n / NSC;
        int jj = n - sym * NSC;
        size_t colR = (size_t)sym * FFT + sc[jj];
        size_t colI = (size_t)M_DIM * ROWLEN + colR;
#pragma unroll
        for (int i = 0; i < 2; ++i) {
            int m0 = bm * BM + wm + i * 16 + rq * 4;
#pragma unroll
            for (int r = 0; r < 4; ++r) {
                float vr = aRR[i][j][r] + aII[i][j][r];
                float vi = aIR[i][j][r] - aRI[i][j][r];
                out[colR + (size_t)(m0 + r) * ROWLEN] = vr;
                out[colI + (size_t)(m0 + r) * ROWLEN] = vi;
            }
        }
    }
}

// ---------------------------------------------------------------------------
extern "C" void kernel_launch(void* const* d_in, const int* in_sizes, int n_in,
                              void* d_out, int out_size, void* d_ws, size_t ws_size,
                              hipStream_t stream) {
    const float* xr = (const float*)d_in[0];
    const float* xi = (const float*)d_in[1];
    const float* Cr = (const float*)d_in[2];
    const float* Ci = (const float*)d_in[3];
    const int* sc   = (const int*)d_in[4];
    float* out = (float*)d_out;

    half_t* Ah = (half_t*)d_ws;                                      // 12.58 MB
    half_t* Wh = (half_t*)((char*)d_ws + (size_t)M_DIM * K_DIM * 2); // 9.44 MB

    prep_all<<<PREP_BLOCKS, 256, 0, stream>>>(
        xr, xi, Cr, Ci, sc, Ah, Wh, out);

    gemm_scatter<<<768, 256, 0, stream>>>(Ah, Wh, sc, out);
}